// Round 4
// baseline (423.091 us; speedup 1.0000x reference)
//
#include <hip/hip_runtime.h>
#include <hip/hip_bf16.h>

#define B_DIM 4096
#define K_TOT 2048   // IN + H
#define H_DIM 1024

typedef short bf16x8 __attribute__((ext_vector_type(8)));
typedef float f32x4 __attribute__((ext_vector_type(4)));
typedef unsigned short u16x8 __attribute__((ext_vector_type(8)));

static __device__ __forceinline__ unsigned short f2bf(float f) {
  union { float f; unsigned u; } v; v.f = f;
  unsigned r = v.u + 0x7FFF + ((v.u >> 16) & 1);  // RNE
  return (unsigned short)(r >> 16);
}

// ---- one pack kernel: blocks [0,4096) pack A=[x|h], [4096,8192) pack W ----
__global__ void pack_all(const float* __restrict__ x, const float* __restrict__ hp,
                         const float* __restrict__ W0, const float* __restrict__ W1,
                         const float* __restrict__ W2, const float* __restrict__ W3,
                         const float* __restrict__ W4, const float* __restrict__ W5,
                         const float* __restrict__ W6, const float* __restrict__ W7,
                         u16x8* __restrict__ A, u16x8* __restrict__ Wc) {
  int blk = blockIdx.x;
  const float* src;
  u16x8* dst;
  int t;
  if (blk < 4096) {
    t = blk * blockDim.x + threadIdx.x;
    int idx = t << 3;
    int b = idx >> 11;
    int k = idx & 2047;
    src = (k < 1024) ? (x + b * 1024 + k) : (hp + b * 1024 + (k - 1024));
    dst = A + t;
  } else {
    t = (blk - 4096) * blockDim.x + threadIdx.x;
    int idx = t << 3;
    int n = idx >> 11;                // output row (gate*1024 + j)
    int k = idx & 2047;
    int gate = n >> 10;
    int j = n & 1023;
    int s = (k < 1024) ? gate : gate + 4;
    const float* base =
        (s == 0) ? W0 : (s == 1) ? W1 : (s == 2) ? W2 : (s == 3) ? W3 :
        (s == 4) ? W4 : (s == 5) ? W5 : (s == 6) ? W6 : W7;
    src = base + j * 1024 + (k & 1023);
    dst = Wc + t;
  }
  float4 lo = *(const float4*)src;
  float4 hi = *(const float4*)(src + 4);
  u16x8 v;
  v[0] = f2bf(lo.x); v[1] = f2bf(lo.y); v[2] = f2bf(lo.z); v[3] = f2bf(lo.w);
  v[4] = f2bf(hi.x); v[5] = f2bf(hi.y); v[6] = f2bf(hi.z); v[7] = f2bf(hi.w);
  *dst = v;
}

// ------------- barrier-free fused GEMM + LSTM -------------
// No LDS. Each wave loads its MFMA fragments straight from global (row-major
// layout matches the 16x16x32 A/B fragment pattern: lane = (row=lane&15,
// kgroup=lane>>4) -> one dwordx4 per fragment). L1/L2 serve the heavy reuse
// (A re-read by 16 j-blocks via L2, W by 64 m-strips). Zero barriers: latency
// hidden purely by wave TLP.
// Wave tile: 64 m-rows x (4 gates x 16 j). Block = 4 waves sharing the 64-row
// A strip (L1 reuse), covering 64 j.
static __device__ __forceinline__ float sigm(float x) {
  return 1.0f / (1.0f + __expf(-x));
}
static __device__ __forceinline__ float tanh_fast(float x) {
  x = fminf(fmaxf(x, -15.f), 15.f);
  float t = __expf(-2.0f * x);
  return (1.0f - t) / (1.0f + t);
}

__global__ __launch_bounds__(256) void gemm_lstm(
    const unsigned short* __restrict__ A,   // B x 2048 bf16
    const unsigned short* __restrict__ W,   // 4096 x 2048 bf16, gate-major rows
    const float* __restrict__ cp,
    const float* __restrict__ bii, const float* __restrict__ bif,
    const float* __restrict__ big, const float* __restrict__ bio,
    float* __restrict__ out) {
  const int wave = threadIdx.x >> 6;
  const int lane = threadIdx.x & 63;
  const int m0 = blockIdx.y << 6;                       // 64-row strip (shared)
  const int j0 = (blockIdx.x << 6) + (wave << 4);       // 16 j per wave
  const int fr = lane & 15;                             // fragment row
  const int gg = lane >> 4;                             // k-group (8 elems)

  const unsigned short* aB = A + (long)(m0 + fr) * K_TOT + gg * 8;
  const unsigned short* bB = W + (long)(j0 + fr) * K_TOT + gg * 8;

  f32x4 acc[4][4];
#pragma unroll
  for (int mi = 0; mi < 4; ++mi)
#pragma unroll
    for (int ni = 0; ni < 4; ++ni)
      acc[mi][ni] = (f32x4){0.f, 0.f, 0.f, 0.f};

#pragma unroll 2
  for (int k0 = 0; k0 < K_TOT; k0 += 32) {
    bf16x8 af[4], bfv[4];
#pragma unroll
    for (int i = 0; i < 4; ++i) {
      af[i]  = *(const bf16x8*)(aB + (long)(i * 16) * K_TOT + k0);
      bfv[i] = *(const bf16x8*)(bB + (long)(i * 1024) * K_TOT + k0);
    }
#pragma unroll
    for (int mi = 0; mi < 4; ++mi)
#pragma unroll
      for (int ni = 0; ni < 4; ++ni)
        acc[mi][ni] = __builtin_amdgcn_mfma_f32_16x16x32_bf16(af[mi], bfv[ni], acc[mi][ni], 0, 0, 0);
  }

  // ---- fused LSTM epilogue
  // C/D layout: col=lane&15, row=(lane>>4)*4+reg  [m89/m91 verified]
  const int ccol = lane & 15;
  const int crow = (lane >> 4) * 4;
  const int j = j0 + ccol;
  const float bi = bii[j];
  const float bff = bif[j];
  const float bg = big[j];
  const float bo = bio[j];
  const long BH = (long)B_DIM * H_DIM;
#pragma unroll
  for (int mi = 0; mi < 4; ++mi) {
#pragma unroll
    for (int reg = 0; reg < 4; ++reg) {
      const int row = m0 + mi * 16 + crow + reg;
      const long p = (long)row * H_DIM + j;
      const float cvp = cp[p];
      const float iv = sigm(acc[mi][0][reg] + bi);
      const float fv = sigm(acc[mi][1][reg] + bff);
      const float gv = tanh_fast(acc[mi][2][reg] + bg);
      const float ov = sigm(acc[mi][3][reg] + bo);
      const float cv = fv * cvp + iv * gv;
      const float hv = ov * tanh_fast(cv);
      out[p]          = hv;
      out[BH + p]     = cv;
      out[2 * BH + p] = iv;
      out[3 * BH + p] = fv;
      out[4 * BH + p] = gv;
      out[5 * BH + p] = ov;
    }
  }
}

extern "C" void kernel_launch(void* const* d_in, const int* in_sizes, int n_in,
                              void* d_out, int out_size, void* d_ws, size_t ws_size,
                              hipStream_t stream) {
  const float* x    = (const float*)d_in[0];
  const float* h    = (const float*)d_in[1];
  const float* c    = (const float*)d_in[2];
  const float* W_ii = (const float*)d_in[3];
  const float* b_ii = (const float*)d_in[4];
  const float* W_if = (const float*)d_in[5];
  const float* b_if = (const float*)d_in[6];
  const float* W_ig = (const float*)d_in[7];
  const float* b_ig = (const float*)d_in[8];
  const float* W_io = (const float*)d_in[9];
  const float* b_io = (const float*)d_in[10];
  const float* W_hi = (const float*)d_in[11];
  const float* W_hf = (const float*)d_in[12];
  const float* W_hg = (const float*)d_in[13];
  const float* W_ho = (const float*)d_in[14];

  // workspace: A_cat bf16 16MB | W_cat bf16 16MB
  unsigned short* Abf = (unsigned short*)d_ws;
  unsigned short* Wbf = (unsigned short*)((char*)d_ws + (size_t)16 * 1024 * 1024);

  pack_all<<<8192, 256, 0, stream>>>(x, h, W_ii, W_if, W_ig, W_io,
                                     W_hi, W_hf, W_hg, W_ho,
                                     (u16x8*)Abf, (u16x8*)Wbf);
  dim3 grid(H_DIM / 64, B_DIM / 64);   // 16 x 64 = 1024 blocks, 4 waves each
  gemm_lstm<<<grid, 256, 0, stream>>>(Abf, Wbf, c, b_ii, b_if, b_ig, b_io,
                                      (float*)d_out);
}

// Round 5
// 284.832 us; speedup vs baseline: 1.4854x; 1.4854x over previous
//
#include <hip/hip_runtime.h>
#include <hip/hip_bf16.h>

#define B_DIM 4096
#define K_TOT 2048   // IN + H
#define H_DIM 1024

typedef short bf16x8 __attribute__((ext_vector_type(8)));
typedef float f32x4 __attribute__((ext_vector_type(4)));
typedef unsigned short u16x8 __attribute__((ext_vector_type(8)));

static __device__ __forceinline__ unsigned short f2bf(float f) {
  union { float f; unsigned u; } v; v.f = f;
  unsigned r = v.u + 0x7FFF + ((v.u >> 16) & 1);  // RNE
  return (unsigned short)(r >> 16);
}

// ---- pack A and W into FRAGMENT-MAJOR bf16 layout ----
// Entry u (16B, 8 bf16): tile = u>>12 (16 rows of m or n), kblk = (u>>6)&63
// (32 k), lane = u&63 with row = lane&15, kgrp = lane>>4.
// Flat byte offset = u*16. A wave's MFMA fragment load is then ONE
// global_load_dwordx4 over 64 consecutive lane-entries (1KB contiguous).
__global__ void pack_all(const float* __restrict__ x, const float* __restrict__ hp,
                         const float* __restrict__ W0, const float* __restrict__ W1,
                         const float* __restrict__ W2, const float* __restrict__ W3,
                         const float* __restrict__ W4, const float* __restrict__ W5,
                         const float* __restrict__ W6, const float* __restrict__ W7,
                         u16x8* __restrict__ Af, u16x8* __restrict__ Wf) {
  int t = blockIdx.x * blockDim.x + threadIdx.x;   // 0 .. 2M
  const int isA = t < (1 << 20);
  int u = t & ((1 << 20) - 1);
  int tile = u >> 12;            // 0..255
  int kblk = (u >> 6) & 63;
  int row  = u & 15;
  int kgrp = (u >> 4) & 3;
  int k = kblk * 32 + kgrp * 8;
  const float* src;
  if (isA) {
    int m = (tile << 4) | row;
    src = (k < 1024) ? (x + m * 1024 + k) : (hp + m * 1024 + (k - 1024));
  } else {
    int n = (tile << 4) | row;     // gate*1024 + j
    int gate = n >> 10;
    int j = n & 1023;
    int s = (k < 1024) ? gate : gate + 4;
    const float* base =
        (s == 0) ? W0 : (s == 1) ? W1 : (s == 2) ? W2 : (s == 3) ? W3 :
        (s == 4) ? W4 : (s == 5) ? W5 : (s == 6) ? W6 : W7;
    src = base + j * 1024 + (k & 1023);
  }
  float4 lo = *(const float4*)src;
  float4 hi = *(const float4*)(src + 4);
  u16x8 v;
  v[0] = f2bf(lo.x); v[1] = f2bf(lo.y); v[2] = f2bf(lo.z); v[3] = f2bf(lo.w);
  v[4] = f2bf(hi.x); v[5] = f2bf(hi.y); v[6] = f2bf(hi.z); v[7] = f2bf(hi.w);
  (isA ? Af : Wf)[u] = v;
}

// ------------- barrier-free fused GEMM + LSTM, fragment-major inputs -------------
// No LDS, no barriers. Every fragment load is one coalesced dwordx4 (1KB/wave).
// Wave tile: 64 m x (4 gates x 16 j). Block = 4 waves sharing the A strip.
// Grid x = m-blocks (consecutive blocks share the same 1MB W slice per XCD L2).
static __device__ __forceinline__ float sigm(float x) {
  return 1.0f / (1.0f + __expf(-x));
}
static __device__ __forceinline__ float tanh_fast(float x) {
  x = fminf(fmaxf(x, -15.f), 15.f);
  float t = __expf(-2.0f * x);
  return (1.0f - t) / (1.0f + t);
}

__global__ __launch_bounds__(256) void gemm_lstm(
    const char* __restrict__ Af,   // fragment-major A
    const char* __restrict__ Wf,   // fragment-major W
    const float* __restrict__ cp,
    const float* __restrict__ bii, const float* __restrict__ bif,
    const float* __restrict__ big, const float* __restrict__ bio,
    float* __restrict__ out) {
  const int wave = threadIdx.x >> 6;
  const int lane = threadIdx.x & 63;
  const int mb = blockIdx.x;               // 0..63 (64 m-rows each)
  const int jb = blockIdx.y;               // 0..15
  const int jw = jb * 4 + wave;            // 16-j block index 0..63

  // mtile i: (mb*4 + i) << 16 bytes; ntile (gate g): (g*64 + jw) << 16
  const char* aBase = Af + ((long)(mb * 4) << 16) + lane * 16;
  const char* bBase = Wf + ((long)jw << 16) + lane * 16;

  f32x4 acc[4][4];
#pragma unroll
  for (int mi = 0; mi < 4; ++mi)
#pragma unroll
    for (int ni = 0; ni < 4; ++ni)
      acc[mi][ni] = (f32x4){0.f, 0.f, 0.f, 0.f};

#pragma unroll 2
  for (int kb = 0; kb < 64; ++kb) {
    const long ko = (long)kb << 10;        // kblk * 1024 bytes
    bf16x8 af[4], bfv[4];
#pragma unroll
    for (int i = 0; i < 4; ++i)
      af[i] = *(const bf16x8*)(aBase + ((long)i << 16) + ko);
#pragma unroll
    for (int g = 0; g < 4; ++g)
      bfv[g] = *(const bf16x8*)(bBase + ((long)g << 22) + ko);
#pragma unroll
    for (int mi = 0; mi < 4; ++mi)
#pragma unroll
      for (int ni = 0; ni < 4; ++ni)
        acc[mi][ni] = __builtin_amdgcn_mfma_f32_16x16x32_bf16(af[mi], bfv[ni], acc[mi][ni], 0, 0, 0);
  }

  // ---- fused LSTM epilogue
  // C/D layout: col(n)=lane&15, row(m)=(lane>>4)*4+reg  [m89/m91 verified]
  const int ccol = lane & 15;
  const int crow = (lane >> 4) * 4;
  const int j = jw * 16 + ccol;
  const float bi = bii[j];
  const float bff = bif[j];
  const float bg = big[j];
  const float bo = bio[j];
  const long BH = (long)B_DIM * H_DIM;
#pragma unroll
  for (int mi = 0; mi < 4; ++mi) {
#pragma unroll
    for (int reg = 0; reg < 4; ++reg) {
      const int row = mb * 64 + mi * 16 + crow + reg;
      const long p = (long)row * H_DIM + j;
      const float cvp = cp[p];
      const float iv = sigm(acc[mi][0][reg] + bi);
      const float fv = sigm(acc[mi][1][reg] + bff);
      const float gv = tanh_fast(acc[mi][2][reg] + bg);
      const float ov = sigm(acc[mi][3][reg] + bo);
      const float cv = fv * cvp + iv * gv;
      const float hv = ov * tanh_fast(cv);
      out[p]          = hv;
      out[BH + p]     = cv;
      out[2 * BH + p] = iv;
      out[3 * BH + p] = fv;
      out[4 * BH + p] = gv;
      out[5 * BH + p] = ov;
    }
  }
}

extern "C" void kernel_launch(void* const* d_in, const int* in_sizes, int n_in,
                              void* d_out, int out_size, void* d_ws, size_t ws_size,
                              hipStream_t stream) {
  const float* x    = (const float*)d_in[0];
  const float* h    = (const float*)d_in[1];
  const float* c    = (const float*)d_in[2];
  const float* W_ii = (const float*)d_in[3];
  const float* b_ii = (const float*)d_in[4];
  const float* W_if = (const float*)d_in[5];
  const float* b_if = (const float*)d_in[6];
  const float* W_ig = (const float*)d_in[7];
  const float* b_ig = (const float*)d_in[8];
  const float* W_io = (const float*)d_in[9];
  const float* b_io = (const float*)d_in[10];
  const float* W_hi = (const float*)d_in[11];
  const float* W_hf = (const float*)d_in[12];
  const float* W_hg = (const float*)d_in[13];
  const float* W_ho = (const float*)d_in[14];

  // workspace: Af bf16 16MB | Wf bf16 16MB  (fragment-major)
  u16x8* Af = (u16x8*)d_ws;
  u16x8* Wf = (u16x8*)((char*)d_ws + (size_t)16 * 1024 * 1024);

  pack_all<<<8192, 256, 0, stream>>>(x, h, W_ii, W_if, W_ig, W_io,
                                     W_hi, W_hf, W_hg, W_ho, Af, Wf);
  dim3 grid(B_DIM / 64, H_DIM / 64);   // 64 x 16 = 1024 blocks, 4 waves each
  gemm_lstm<<<grid, 256, 0, stream>>>((const char*)Af, (const char*)Wf, c,
                                      b_ii, b_if, b_ig, b_io, (float*)d_out);
}